// Round 6
// baseline (156.135 us; speedup 1.0000x reference)
//
#include <hip/hip_runtime.h>

#define EPS 1e-10f

constexpr int B_ = 64, K_ = 4, M_ = 3, P_ = 65536;
constexpr int THREADS = 256;
constexpr int CHUNK = 2048;                    // pass1 pixels per block
constexpr int BLOCKS_PER_B = P_ / CHUNK;       // 32 -> 2048 blocks
constexpr int VPT = CHUNK / 4 / THREADS;       // 2 float4 iters/thread
constexpr int NACC = 29;                       // 4 s + 12 t + 12 u + 1 n

// pass3 staging geometry (R5 structure, kept)
constexpr int P3CHUNK = 4096;
constexpr int P3BPB = P_ / P3CHUNK;            // 16 -> 1024 blocks
constexpr int TILE = 512;
constexpr int NT = P3CHUNK / TILE;
constexpr int NPL = 8;

// ================= pass1 ablation: template<MODE> ==========================
// MODE 0: full (correct)   MODE 1: loads-only (asm-sunk)
// MODE 2: math-only (synthesized operands)   MODE 3: loads + 1 accumulator
template<int MODE>
__global__ __launch_bounds__(THREADS) void p1v(
    const float* __restrict__ pred, const float* __restrict__ inp,
    const int* __restrict__ heart, float* __restrict__ dst)
{
    const int blk   = blockIdx.x;
    const int b     = blk / BLOCKS_PER_B;
    const int chunk = blk % BLOCKS_PER_B;
    const int tid   = threadIdx.x;

    const float4* pb = (const float4*)(pred + (size_t)b * K_ * P_);
    const float4* ib = (const float4*)(inp  + (size_t)b * M_ * P_);
    const int4*   hb = (const int4*)(heart + (size_t)b * P_);
    const int vbase = chunk * (CHUNK / 4);

    float sacc[K_], tacc[K_][M_], uacc[K_][M_];
    float nacc = 0.f, one = 0.f;
    #pragma unroll
    for (int k = 0; k < K_; ++k) {
        sacc[k] = 0.f;
        #pragma unroll
        for (int m = 0; m < M_; ++m) { tacc[k][m] = 0.f; uacc[k][m] = 0.f; }
    }

    #pragma unroll
    for (int it = 0; it < VPT; ++it) {
        const int v = vbase + it * THREADS + tid;
        int4 h4; float4 pk[K_]; float4 xm[M_];
        if constexpr (MODE != 2) {
            h4 = hb[v];
            #pragma unroll
            for (int k = 0; k < K_; ++k) pk[k] = pb[k * (P_ / 4) + v];
            #pragma unroll
            for (int m = 0; m < M_; ++m) xm[m] = ib[m * (P_ / 4) + v];
        } else {
            const unsigned q = (unsigned)v * 2654435761u + tid;
            h4.x = (q & 2) ? 1 : 0; h4.y = (q & 4) ? 1 : 0;
            h4.z = (q & 8) ? 1 : 0; h4.w = 1;
            #pragma unroll
            for (int k = 0; k < K_; ++k) {
                const float base = (float)((q >> (k & 7)) & 1023) * 0.001f;
                pk[k] = make_float4(base, base + 0.1f, base + 0.2f, base + 0.3f);
            }
            #pragma unroll
            for (int m = 0; m < M_; ++m) {
                const float base = (float)((q >> (m + 4)) & 2047) * 0.0005f;
                xm[m] = make_float4(base, base - 0.1f, base + 0.2f, base - 0.3f);
            }
        }

        if constexpr (MODE == 1) {
            #pragma unroll
            for (int k = 0; k < K_; ++k)
                asm volatile("" :: "v"(pk[k].x), "v"(pk[k].y), "v"(pk[k].z), "v"(pk[k].w));
            #pragma unroll
            for (int m = 0; m < M_; ++m)
                asm volatile("" :: "v"(xm[m].x), "v"(xm[m].y), "v"(xm[m].z), "v"(xm[m].w));
            nacc += ((h4.x == 1) ? 1.f : 0.f) + ((h4.y == 1) ? 1.f : 0.f)
                  + ((h4.z == 1) ? 1.f : 0.f) + ((h4.w == 1) ? 1.f : 0.f);
        } else if constexpr (MODE == 3) {
            #define PIXONE(C) do {                                            \
                const float w = (h4.C == 1) ? 1.f : 0.f;                      \
                one = fmaf(w, pk[0].C + pk[1].C + pk[2].C + pk[3].C           \
                            + xm[0].C + xm[1].C + xm[2].C, one);              \
            } while (0)
            PIXONE(x); PIXONE(y); PIXONE(z); PIXONE(w);
            #undef PIXONE
        } else {
            #define PIX1(C) do {                                              \
                const float w = (h4.C == 1) ? 1.f : 0.f;                      \
                nacc += w;                                                    \
                _Pragma("unroll")                                             \
                for (int k = 0; k < K_; ++k) {                                \
                    const float pw = pk[k].C * w;                             \
                    sacc[k] += pw;                                            \
                    _Pragma("unroll")                                         \
                    for (int m = 0; m < M_; ++m) {                            \
                        const float x = xm[m].C;                              \
                        tacc[k][m] = fmaf(pw,     x, tacc[k][m]);             \
                        uacc[k][m] = fmaf(pw * x, x, uacc[k][m]);             \
                    }                                                         \
                }                                                             \
            } while (0)
            PIX1(x); PIX1(y); PIX1(z); PIX1(w);
            #undef PIX1
        }
    }

    __shared__ float lds[4][NACC];
    const int lane = tid & 63, wid = tid >> 6;

    if constexpr (MODE == 0 || MODE == 2) {
        float acc[NACC];
        #pragma unroll
        for (int k = 0; k < K_; ++k) {
            acc[k] = sacc[k];
            #pragma unroll
            for (int m = 0; m < M_; ++m) {
                acc[4  + k * M_ + m] = tacc[k][m];
                acc[16 + k * M_ + m] = uacc[k][m];
            }
        }
        acc[28] = nacc;
        #pragma unroll
        for (int i = 0; i < NACC; ++i) {
            float x = acc[i];
            #pragma unroll
            for (int off = 32; off; off >>= 1) x += __shfl_down(x, off);
            if (lane == 0) lds[wid][i] = x;
        }
        __syncthreads();
        if (tid < NACC) {
            const float x = lds[0][tid] + lds[1][tid] + lds[2][tid] + lds[3][tid];
            atomicAdd(&dst[b * NACC + tid], x);
        }
    } else {
        float x = (MODE == 1) ? nacc : one;
        #pragma unroll
        for (int off = 32; off; off >>= 1) x += __shfl_down(x, off);
        if (lane == 0) lds[wid][0] = x;
        __syncthreads();
        if (tid == 0)
            atomicAdd(&dst[MODE], lds[0][0] + lds[1][0] + lds[2][0] + lds[3][0]);
    }
}

// ================= pass 2 ==================================================
__global__ void gmm_pass2(const float* __restrict__ sums, float* __restrict__ der)
{
    const int t = blockIdx.x * blockDim.x + threadIdx.x;
    if (t >= B_ * K_) return;
    const int b = t / K_, k = t % K_;
    const float* sb = sums + b * NACC;
    float* db = der + b * NACC;

    const float s = sb[k] + EPS;
    const float inv_s = 1.f / s;
    float c = 1.f;
    #pragma unroll
    for (int m = 0; m < M_; ++m) {
        const float tkm = sb[4  + k * M_ + m];
        const float ukm = sb[16 + k * M_ + m];
        const float mu  = tkm * inv_s;
        const float var = fmaf(-mu, mu, ukm * inv_s) + EPS;
        db[k * M_ + m]      = mu;
        db[12 + k * M_ + m] = 0.5f / var;
        c *= rsqrtf(6.283185307179586f * var);
    }
    db[24 + k] = c;
    if (k == 0) db[28] = 1.f / (sb[28] * (float)B_);
}

// ================= pass 3 (R5 staged version, unchanged) ===================
__device__ __forceinline__ void stage_tile(
    const float* __restrict__ pred, const float* __restrict__ inp,
    const int* __restrict__ heart, int b, int pix0,
    float (*sbuf)[NPL][TILE], int buf, int wv, int lane)
{
    #pragma unroll
    for (int j = 0; j < 4; ++j) {
        const int r  = wv * 4 + j;
        const int pl = r >> 1;
        const int hf = r & 1;
        const float* g;
        if (pl < 4)       g = pred + ((size_t)(b * K_ + pl)) * P_ + pix0 + hf * 256;
        else if (pl < 7)  g = inp  + ((size_t)(b * M_ + (pl - 4))) * P_ + pix0 + hf * 256;
        else              g = (const float*)(heart + (size_t)b * P_ + pix0 + hf * 256);
        __builtin_amdgcn_global_load_lds(g + lane * 4, &sbuf[buf][pl][hf * 256], 16, 0, 0);
    }
}

__global__ __launch_bounds__(THREADS, 3) void gmm_pass3(
    const float* __restrict__ pred, const float* __restrict__ inp,
    const int* __restrict__ heart, const float* __restrict__ der,
    float* __restrict__ out)
{
    __shared__ float sbuf[2][NPL][TILE];
    const int blk   = blockIdx.x;
    const int b     = blk / P3BPB;
    const int chunk = blk % P3BPB;
    const int tid   = threadIdx.x;
    const int wv    = tid >> 6;
    const int lane  = tid & 63;
    const int base  = chunk * P3CHUNK;

    const float* db = der + b * NACC;
    float mu[K_][M_], iv[K_][M_], ck[K_];
    #pragma unroll
    for (int k = 0; k < K_; ++k) {
        #pragma unroll
        for (int m = 0; m < M_; ++m) {
            mu[k][m] = db[k * M_ + m];
            iv[k][m] = db[12 + k * M_ + m];
        }
        ck[k] = db[24 + k];
    }
    const float invn = db[28];

    float part = 0.f;

    stage_tile(pred, inp, heart, b, base, sbuf, 0, wv, lane);
    __syncthreads();

    for (int t = 0; t < NT; ++t) {
        const int cur = t & 1;
        if (t + 1 < NT)
            stage_tile(pred, inp, heart, b, base + (t + 1) * TILE, sbuf, cur ^ 1, wv, lane);
        __builtin_amdgcn_sched_barrier(0);

        const int* hp = (const int*)&sbuf[cur][7][0];
        #pragma unroll
        for (int i = 0; i < TILE / THREADS; ++i) {
            const int px = i * THREADS + tid;
            const float w = (hp[px] == 1) ? 1.f : 0.f;
            const float x0 = sbuf[cur][4][px];
            const float x1 = sbuf[cur][5][px];
            const float x2 = sbuf[cur][6][px];
            float mix = EPS;
            #pragma unroll
            for (int k = 0; k < K_; ++k) {
                const float d0 = x0 - mu[k][0];
                const float d1 = x1 - mu[k][1];
                const float d2 = x2 - mu[k][2];
                float e = -(d0 * d0) * iv[k][0];
                e = fmaf(-(d1 * d1), iv[k][1], e);
                e = fmaf(-(d2 * d2), iv[k][2], e);
                mix = fmaf(sbuf[cur][k][px] * ck[k], __expf(e), mix);
            }
            part = fmaf(w, __logf(mix), part);
        }
        __syncthreads();
    }

    __shared__ float lds[4];
    float v = part;
    #pragma unroll
    for (int off = 32; off; off >>= 1) v += __shfl_down(v, off);
    if (lane == 0) lds[wv] = v;
    __syncthreads();
    if (tid == 0) {
        const float ssum = lds[0] + lds[1] + lds[2] + lds[3];
        atomicAdd(out, -ssum * invn);
    }
}

extern "C" void kernel_launch(void* const* d_in, const int* in_sizes, int n_in,
                              void* d_out, int out_size, void* d_ws, size_t ws_size,
                              hipStream_t stream)
{
    const float* pred  = (const float*)d_in[0];
    const float* inp   = (const float*)d_in[1];
    const int*   heart = (const int*)d_in[2];
    float* out = (float*)d_out;
    float* ws  = (float*)d_ws;

    float* sums = ws;                 // B*29 floats (real)
    float* der  = ws + B_ * NACC;     // B*29 floats (real)
    float* junk = ws + 8192;          // ablation sink, never read

    hipMemsetAsync(sums, 0, B_ * NACC * sizeof(float), stream);
    hipMemsetAsync(out,  0, sizeof(float), stream);

    p1v<0><<<B_ * BLOCKS_PER_B, THREADS, 0, stream>>>(pred, inp, heart, sums);
    p1v<1><<<B_ * BLOCKS_PER_B, THREADS, 0, stream>>>(pred, inp, heart, junk);
    p1v<2><<<B_ * BLOCKS_PER_B, THREADS, 0, stream>>>(pred, inp, heart, junk);
    p1v<3><<<B_ * BLOCKS_PER_B, THREADS, 0, stream>>>(pred, inp, heart, junk);
    gmm_pass2<<<1, 256, 0, stream>>>(sums, der);
    gmm_pass3<<<B_ * P3BPB, THREADS, 0, stream>>>(pred, inp, heart, der, out);
}

// Round 7
// 79.975 us; speedup vs baseline: 1.9523x; 1.9523x over previous
//
#include <hip/hip_runtime.h>

#define EPS 1e-10f

constexpr int B_ = 64, K_ = 4, M_ = 3, P_ = 65536;
constexpr int THREADS = 256;
constexpr int CHUNK = 2048;                 // pixels per block (streaming passes)
constexpr int BPB = P_ / CHUNK;             // 32 -> 2048 blocks
constexpr int VPT = CHUNK / 4 / THREADS;    // 2 float4 iters per thread
constexpr int NS = 32;                      // sums stride: s0..3 t4..15 u16..27 n28

// ---- k_count: per-b ROI pixel count. Ideal ~3 us. Doubles as ramp probe. ----
__global__ __launch_bounds__(THREADS) void k_count(
    const int* __restrict__ heart, float* __restrict__ sums)
{
    const int b   = blockIdx.x >> 4;          // 16 segs per b
    const int seg = blockIdx.x & 15;
    const int tid = threadIdx.x;
    const int4* hb = (const int4*)(heart + (size_t)b * P_) + seg * (P_ / 4 / 16);

    float n = 0.f;
    #pragma unroll
    for (int i = 0; i < 4; ++i) {
        const int4 h = hb[i * THREADS + tid];
        n += (float)((h.x == 1) + (h.y == 1) + (h.z == 1) + (h.w == 1));
    }

    __shared__ float lds[4];
    const int lane = tid & 63, wid = tid >> 6;
    #pragma unroll
    for (int off = 32; off; off >>= 1) n += __shfl_down(n, off);
    if (lane == 0) lds[wid] = n;
    __syncthreads();
    if (tid == 0)
        atomicAdd(&sums[b * NS + 28], lds[0] + lds[1] + lds[2] + lds[3]);
}

// ---- k_stats: per-(b,k) weighted sums (28 accumulators) ---------------------
__global__ __launch_bounds__(THREADS) void k_stats(
    const float* __restrict__ pred, const float* __restrict__ inp,
    const int* __restrict__ heart, float* __restrict__ sums)
{
    const int blk   = blockIdx.x;
    const int b     = blk / BPB;
    const int chunk = blk % BPB;
    const int tid   = threadIdx.x;

    const float4* pb = (const float4*)(pred + (size_t)b * K_ * P_);
    const float4* ib = (const float4*)(inp  + (size_t)b * M_ * P_);
    const int4*   hb = (const int4*)(heart + (size_t)b * P_);
    const int vbase = chunk * (CHUNK / 4);

    float sacc[K_], tacc[K_][M_], uacc[K_][M_];
    #pragma unroll
    for (int k = 0; k < K_; ++k) {
        sacc[k] = 0.f;
        #pragma unroll
        for (int m = 0; m < M_; ++m) { tacc[k][m] = 0.f; uacc[k][m] = 0.f; }
    }

    #pragma unroll
    for (int it = 0; it < VPT; ++it) {
        const int v = vbase + it * THREADS + tid;
        const int4 h4 = hb[v];
        float4 pk[K_];
        float4 xm[M_];
        #pragma unroll
        for (int k = 0; k < K_; ++k) pk[k] = pb[k * (P_ / 4) + v];
        #pragma unroll
        for (int m = 0; m < M_; ++m) xm[m] = ib[m * (P_ / 4) + v];

        #define PIX1(C) do {                                                  \
            const float w = (h4.C == 1) ? 1.f : 0.f;                          \
            _Pragma("unroll")                                                 \
            for (int k = 0; k < K_; ++k) {                                    \
                const float pw = pk[k].C * w;                                 \
                sacc[k] += pw;                                                \
                _Pragma("unroll")                                             \
                for (int m = 0; m < M_; ++m) {                                \
                    const float x = xm[m].C;                                  \
                    tacc[k][m] = fmaf(pw,     x, tacc[k][m]);                 \
                    uacc[k][m] = fmaf(pw * x, x, uacc[k][m]);                 \
                }                                                             \
            }                                                                 \
        } while (0)
        PIX1(x); PIX1(y); PIX1(z); PIX1(w);
        #undef PIX1
    }

    float acc[28];
    #pragma unroll
    for (int k = 0; k < K_; ++k) {
        acc[k] = sacc[k];
        #pragma unroll
        for (int m = 0; m < M_; ++m) {
            acc[4  + k * M_ + m] = tacc[k][m];
            acc[16 + k * M_ + m] = uacc[k][m];
        }
    }

    __shared__ float lds[4][28];
    const int lane = tid & 63, wid = tid >> 6;
    #pragma unroll
    for (int i = 0; i < 28; ++i) {
        float x = acc[i];
        #pragma unroll
        for (int off = 32; off; off >>= 1) x += __shfl_down(x, off);
        if (lane == 0) lds[wid][i] = x;
    }
    __syncthreads();
    if (tid < 28) {
        const float x = lds[0][tid] + lds[1][tid] + lds[2][tid] + lds[3][tid];
        atomicAdd(&sums[b * NS + tid], x);
    }
}

// ---- k_loss: inline pass2 derivation + mixture log-likelihood --------------
__global__ __launch_bounds__(THREADS) void k_loss(
    const float* __restrict__ pred, const float* __restrict__ inp,
    const int* __restrict__ heart, const float* __restrict__ sums,
    float* __restrict__ out)
{
    const int blk   = blockIdx.x;
    const int b     = blk / BPB;
    const int chunk = blk % BPB;
    const int tid   = threadIdx.x;

    // per-thread redundant pass2 math (reads one broadcast cache line)
    const float* sb = sums + b * NS;
    float mu[K_][M_], iv[K_][M_], ck[K_];
    #pragma unroll
    for (int k = 0; k < K_; ++k) {
        const float s = sb[k] + EPS;
        const float inv_s = 1.f / s;
        float c = 1.f;
        #pragma unroll
        for (int m = 0; m < M_; ++m) {
            const float t = sb[4  + k * M_ + m];
            const float u = sb[16 + k * M_ + m];
            const float muv = t * inv_s;
            const float var = fmaf(-muv, muv, u * inv_s) + EPS;
            mu[k][m] = muv;
            iv[k][m] = 0.5f / var;
            c *= rsqrtf(6.283185307179586f * var);
        }
        ck[k] = c;
    }
    const float invn = 1.f / (sb[28] * (float)B_);

    const float4* pb = (const float4*)(pred + (size_t)b * K_ * P_);
    const float4* ib = (const float4*)(inp  + (size_t)b * M_ * P_);
    const int4*   hb = (const int4*)(heart + (size_t)b * P_);
    const int vbase = chunk * (CHUNK / 4);

    float part = 0.f;
    #pragma unroll
    for (int it = 0; it < VPT; ++it) {
        const int v = vbase + it * THREADS + tid;
        const int4 h4 = hb[v];
        float4 pk[K_];
        float4 xm[M_];
        #pragma unroll
        for (int k = 0; k < K_; ++k) pk[k] = pb[k * (P_ / 4) + v];
        #pragma unroll
        for (int m = 0; m < M_; ++m) xm[m] = ib[m * (P_ / 4) + v];

        #define PIX3(C) do {                                                  \
            const float w = (h4.C == 1) ? 1.f : 0.f;                          \
            float mix = EPS;                                                  \
            _Pragma("unroll")                                                 \
            for (int k = 0; k < K_; ++k) {                                    \
                float e = 0.f;                                                \
                _Pragma("unroll")                                             \
                for (int m = 0; m < M_; ++m) {                                \
                    const float d = xm[m].C - mu[k][m];                       \
                    e = fmaf(-(d * d), iv[k][m], e);                          \
                }                                                             \
                mix = fmaf(pk[k].C * ck[k], __expf(e), mix);                  \
            }                                                                 \
            part = fmaf(w, __logf(mix), part);                                \
        } while (0)
        PIX3(x); PIX3(y); PIX3(z); PIX3(w);
        #undef PIX3
    }

    __shared__ float lds[4];
    const int lane = tid & 63, wid = tid >> 6;
    float v = part;
    #pragma unroll
    for (int off = 32; off; off >>= 1) v += __shfl_down(v, off);
    if (lane == 0) lds[wid] = v;
    __syncthreads();
    if (tid == 0) {
        const float ssum = lds[0] + lds[1] + lds[2] + lds[3];
        atomicAdd(out, -ssum * invn);
    }
}

extern "C" void kernel_launch(void* const* d_in, const int* in_sizes, int n_in,
                              void* d_out, int out_size, void* d_ws, size_t ws_size,
                              hipStream_t stream)
{
    const float* pred  = (const float*)d_in[0];
    const float* inp   = (const float*)d_in[1];
    const int*   heart = (const int*)d_in[2];
    float* out  = (float*)d_out;
    float* sums = (float*)d_ws;            // B*32 floats

    hipMemsetAsync(sums, 0, B_ * NS * sizeof(float), stream);
    hipMemsetAsync(out,  0, sizeof(float), stream);

    k_count<<<B_ * 16,  THREADS, 0, stream>>>(heart, sums);
    k_stats<<<B_ * BPB, THREADS, 0, stream>>>(pred, inp, heart, sums);
    k_loss <<<B_ * BPB, THREADS, 0, stream>>>(pred, inp, heart, sums, out);
}